// Round 1
// baseline (2506.505 us; speedup 1.0000x reference)
//
#include <hip/hip_runtime.h>

#define NFEAT 128

// ---------------- degree ----------------
__global__ void deg_kernel(const int* __restrict__ dst, float* __restrict__ deg, int E) {
    int e = blockIdx.x * blockDim.x + threadIdx.x;
    if (e < E) atomicAdd(&deg[dst[e]], 1.0f);
}

// ---------------- scatter-add: sum[dst] += feat[src] ----------------
// one thread per (edge, float4-chunk): 32 threads per edge
__global__ void scatter_kernel(const int* __restrict__ src, const int* __restrict__ dst,
                               const float* __restrict__ feat, float* __restrict__ sum,
                               int E) {
    int tid = blockIdx.x * blockDim.x + threadIdx.x;
    int e = tid >> 5;
    if (e >= E) return;
    int c = (tid & 31) << 2;
    int s = src[e], d = dst[e];
    const float4 v = *reinterpret_cast<const float4*>(feat + (size_t)s * NFEAT + c);
    float* p = sum + (size_t)d * NFEAT + c;
    atomicAdd(p + 0, v.x);
    atomicAdd(p + 1, v.y);
    atomicAdd(p + 2, v.z);
    atomicAdd(p + 3, v.w);
}

// ---------------- fused SAGE GEMM ----------------
// AGG:  out = (sum/max(deg,1)) @ Wl^T + xin @ Wr^T + bias   (K = 256)
// !AGG: out = xin @ Wr^T + bias                             (K = 128)
// RELU: apply relu in epilogue
template <bool AGG, bool RELU>
__global__ __launch_bounds__(256) void sage_gemm(
    const float* __restrict__ Asum, const float* __restrict__ deg,
    const float* __restrict__ xin,
    const float* __restrict__ Wl, const float* __restrict__ Wr,
    const float* __restrict__ bias,
    float* __restrict__ out, int n)
{
    constexpr int K = AGG ? 256 : 128;
    constexpr int BK = 32;
    __shared__ float As[128][BK + 1];
    __shared__ float Ws[128][BK + 1];
    const int t  = threadIdx.x;
    const int m0 = blockIdx.x * 128;
    const int tx = t & 15;       // output-col group
    const int ty = t >> 4;       // node-row group
    const int sr  = t >> 1;      // staging row 0..127
    const int sc0 = (t & 1) * 16;// staging col base (floats)

    float acc[8][8];
#pragma unroll
    for (int i = 0; i < 8; ++i)
#pragma unroll
        for (int j = 0; j < 8; ++j) acc[i][j] = 0.f;

    for (int kc = 0; kc < K / BK; ++kc) {
        const int kb = kc * BK;
        // ---- stage A tile [128 nodes][32 k]
        {
            const int gm = m0 + sr;
            const bool valid = gm < n;
            float id = 1.0f;
            if (AGG && valid && kb < 128) id = 1.0f / fmaxf(deg[gm], 1.0f);
#pragma unroll
            for (int q = 0; q < 4; ++q) {
                const int kk = kb + sc0 + q * 4;
                float4 v = make_float4(0.f, 0.f, 0.f, 0.f);
                if (valid) {
                    if (AGG) {
                        if (kk < 128) {
                            v = *reinterpret_cast<const float4*>(Asum + (size_t)gm * NFEAT + kk);
                            v.x *= id; v.y *= id; v.z *= id; v.w *= id;
                        } else {
                            v = *reinterpret_cast<const float4*>(xin + (size_t)gm * NFEAT + (kk - 128));
                        }
                    } else {
                        v = *reinterpret_cast<const float4*>(xin + (size_t)gm * NFEAT + kk);
                    }
                }
                float* a = &As[sr][sc0 + q * 4];
                a[0] = v.x; a[1] = v.y; a[2] = v.z; a[3] = v.w;
            }
        }
        // ---- stage W tile [128 out][32 k]  (concat Wl|Wr along k)
        {
#pragma unroll
            for (int q = 0; q < 4; ++q) {
                const int kk = kb + sc0 + q * 4;
                const float* wp;
                if (AGG) wp = (kk < 128) ? (Wl + sr * NFEAT + kk)
                                         : (Wr + sr * NFEAT + (kk - 128));
                else     wp = Wr + sr * NFEAT + kk;
                const float4 v = *reinterpret_cast<const float4*>(wp);
                float* w = &Ws[sr][sc0 + q * 4];
                w[0] = v.x; w[1] = v.y; w[2] = v.z; w[3] = v.w;
            }
        }
        __syncthreads();
        // ---- 128x128x32 inner product, 8x8 register tile
        for (int k = 0; k < BK; ++k) {
            float a[8], b[8];
#pragma unroll
            for (int i = 0; i < 8; ++i) a[i] = As[ty * 8 + i][k];
#pragma unroll
            for (int j = 0; j < 8; ++j) b[j] = Ws[tx * 8 + j][k];
#pragma unroll
            for (int i = 0; i < 8; ++i)
#pragma unroll
                for (int j = 0; j < 8; ++j) acc[i][j] += a[i] * b[j];
        }
        __syncthreads();
    }
    // ---- epilogue: bias (+relu), float4 stores
    float bv[8];
#pragma unroll
    for (int j = 0; j < 8; ++j) bv[j] = bias[tx * 8 + j];
#pragma unroll
    for (int i = 0; i < 8; ++i) {
        const int gm = m0 + ty * 8 + i;
        if (gm < n) {
            float o[8];
#pragma unroll
            for (int j = 0; j < 8; ++j) {
                float v = acc[i][j] + bv[j];
                if (RELU) v = fmaxf(v, 0.f);
                o[j] = v;
            }
            float4 v0 = make_float4(o[0], o[1], o[2], o[3]);
            float4 v1 = make_float4(o[4], o[5], o[6], o[7]);
            *reinterpret_cast<float4*>(out + (size_t)gm * NFEAT + tx * 8)     = v0;
            *reinterpret_cast<float4*>(out + (size_t)gm * NFEAT + tx * 8 + 4) = v1;
        }
    }
}

extern "C" void kernel_launch(void* const* d_in, const int* in_sizes, int n_in,
                              void* d_out, int out_size, void* d_ws, size_t ws_size,
                              hipStream_t stream) {
    const float* x     = (const float*)d_in[0];
    const int*   xedge = (const int*)d_in[1];
    const float* w1_l  = (const float*)d_in[2];
    const float* b1_l  = (const float*)d_in[3];
    const float* w1_r  = (const float*)d_in[4];
    const float* w2_l  = (const float*)d_in[5];
    const float* b2_l  = (const float*)d_in[6];
    const float* w2_r  = (const float*)d_in[7];
    const float* w_dec = (const float*)d_in[8];
    const float* b_dec = (const float*)d_in[9];

    const int N = in_sizes[0] / NFEAT;
    const int E = in_sizes[1] / 2;
    const int* src = xedge;
    const int* dst = xedge + E;

    float* h_out  = (float*)d_out;                    // output 0: h [N,128]
    float* dx_out = h_out + (size_t)N * NFEAT;        // output 1: dx [N,128]

    char*  ws    = (char*)d_ws;
    size_t degsz = (((size_t)N * sizeof(float)) + 255) & ~(size_t)255;
    float* deg   = (float*)ws;
    float* sum   = (float*)(ws + degsz);
    float* h1    = sum + (size_t)N * NFEAT;

    hipMemsetAsync(deg, 0, (size_t)N * sizeof(float), stream);
    hipMemsetAsync(sum, 0, (size_t)N * NFEAT * sizeof(float), stream);

    deg_kernel<<<(E + 255) / 256, 256, 0, stream>>>(dst, deg, E);

    const long long swork = (long long)E * 32;
    const int sblocks = (int)((swork + 255) / 256);
    scatter_kernel<<<sblocks, 256, 0, stream>>>(src, dst, x, sum, E);

    const int gblocks = (N + 127) / 128;
    sage_gemm<true, true><<<gblocks, 256, 0, stream>>>(sum, deg, x, w1_l, w1_r, b1_l, h1, N);

    hipMemsetAsync(sum, 0, (size_t)N * NFEAT * sizeof(float), stream);
    scatter_kernel<<<sblocks, 256, 0, stream>>>(src, dst, h1, sum, E);
    sage_gemm<true, false><<<gblocks, 256, 0, stream>>>(sum, deg, h1, w2_l, w2_r, b2_l, h_out, N);

    sage_gemm<false, false><<<gblocks, 256, 0, stream>>>(nullptr, nullptr, h_out, nullptr, w_dec,
                                                         b_dec, dx_out, N);
}

// Round 2
// 617.647 us; speedup vs baseline: 4.0582x; 4.0582x over previous
//
#include <hip/hip_runtime.h>

#define NFEAT 128

// ---------------- degree histogram (int) ----------------
__global__ void hist_kernel(const int* __restrict__ dst, int* __restrict__ deg, int E) {
    int e = blockIdx.x * blockDim.x + threadIdx.x;
    if (e < E) atomicAdd(&deg[dst[e]], 1);
}

// ---------------- exclusive scan, 3-kernel (N=100k -> 98 blocks of 1024) ----------------
__global__ __launch_bounds__(256) void scan_blocks(const int* __restrict__ in, int* __restrict__ out,
                                                   int* __restrict__ bsum, int n) {
    __shared__ int lds[256];
    const int t = threadIdx.x;
    const int base = blockIdx.x * 1024 + t * 4;
    int a[4];
#pragma unroll
    for (int q = 0; q < 4; ++q) a[q] = (base + q < n) ? in[base + q] : 0;
    const int tsum = a[0] + a[1] + a[2] + a[3];
    lds[t] = tsum;
    __syncthreads();
    for (int off = 1; off < 256; off <<= 1) {
        int v = (t >= off) ? lds[t - off] : 0;
        __syncthreads();
        lds[t] += v;
        __syncthreads();
    }
    const int excl = lds[t] - tsum;   // exclusive prefix of this thread's 4 items
    if (t == 255) bsum[blockIdx.x] = lds[255];
    int r = excl;
#pragma unroll
    for (int q = 0; q < 4; ++q) {
        if (base + q < n) out[base + q] = r;
        r += a[q];
    }
}

// single block; valid while nb <= 256 (N=100000 -> nb=98)
__global__ __launch_bounds__(256) void scan_carry(int* __restrict__ bsum, int nb) {
    __shared__ int lds[256];
    const int t = threadIdx.x;
    const int v = (t < nb) ? bsum[t] : 0;
    lds[t] = v;
    __syncthreads();
    for (int off = 1; off < 256; off <<= 1) {
        int u = (t >= off) ? lds[t - off] : 0;
        __syncthreads();
        lds[t] += u;
        __syncthreads();
    }
    if (t < nb) bsum[t] = lds[t] - v;  // exclusive
}

__global__ void scan_add(int* __restrict__ out, const int* __restrict__ bsum, int n, int E) {
    const int i = blockIdx.x * blockDim.x + threadIdx.x;
    if (i < n) out[i] += bsum[i >> 10];
    if (i == 0) out[n] = E;
}

// ---------------- CSR bucket fill: perm[pos[dst]++] = src ----------------
__global__ void fill_csr(const int* __restrict__ src, const int* __restrict__ dst,
                         int* __restrict__ pos, int* __restrict__ perm, int E) {
    const int e = blockIdx.x * blockDim.x + threadIdx.x;
    if (e < E) {
        const int p = atomicAdd(&pos[dst[e]], 1);
        perm[p] = src[e];
    }
}

// ---------------- gather mean: one wave per node ----------------
__global__ __launch_bounds__(256) void gather_mean(const int* __restrict__ row_off,
                                                   const int* __restrict__ perm,
                                                   const float* __restrict__ feat,
                                                   float* __restrict__ out, int n) {
    const int wave = (blockIdx.x * blockDim.x + threadIdx.x) >> 6;
    if (wave >= n) return;
    const int lane = threadIdx.x & 63;
    const int lo = row_off[wave], hi = row_off[wave + 1];
    float ax = 0.f, ay = 0.f;
    for (int i = lo; i < hi; ++i) {
        const int s = perm[i];
        const float2 v = *reinterpret_cast<const float2*>(feat + (size_t)s * NFEAT + lane * 2);
        ax += v.x;
        ay += v.y;
    }
    const float inv = 1.0f / fmaxf((float)(hi - lo), 1.0f);
    *reinterpret_cast<float2*>(out + (size_t)wave * NFEAT + lane * 2) = make_float2(ax * inv, ay * inv);
}

// ---------------- fused SAGE GEMM ----------------
// AGG:  out = mean @ Wl^T + xin @ Wr^T + bias   (K = 256, A = [mean | xin])
// !AGG: out = xin @ Wr^T + bias                 (K = 128)
template <bool AGG, bool RELU>
__global__ __launch_bounds__(256) void sage_gemm(
    const float* __restrict__ Amean, const float* __restrict__ xin,
    const float* __restrict__ Wl, const float* __restrict__ Wr,
    const float* __restrict__ bias,
    float* __restrict__ out, int n)
{
    constexpr int K = AGG ? 256 : 128;
    constexpr int BK = 32;
    __shared__ float As[128][BK + 1];
    __shared__ float Ws[128][BK + 1];
    const int t  = threadIdx.x;
    const int m0 = blockIdx.x * 128;
    const int tx = t & 15;        // output-col group
    const int ty = t >> 4;        // node-row group
    const int sr  = t >> 1;       // staging row 0..127
    const int sc0 = (t & 1) * 16; // staging col base (floats)

    float acc[8][8];
#pragma unroll
    for (int i = 0; i < 8; ++i)
#pragma unroll
        for (int j = 0; j < 8; ++j) acc[i][j] = 0.f;

    for (int kc = 0; kc < K / BK; ++kc) {
        const int kb = kc * BK;
        // ---- stage A tile [128 nodes][32 k]
        {
            const int gm = m0 + sr;
            const bool valid = gm < n;
#pragma unroll
            for (int q = 0; q < 4; ++q) {
                const int kk = kb + sc0 + q * 4;
                float4 v = make_float4(0.f, 0.f, 0.f, 0.f);
                if (valid) {
                    if (AGG) {
                        v = (kk < 128)
                          ? *reinterpret_cast<const float4*>(Amean + (size_t)gm * NFEAT + kk)
                          : *reinterpret_cast<const float4*>(xin + (size_t)gm * NFEAT + (kk - 128));
                    } else {
                        v = *reinterpret_cast<const float4*>(xin + (size_t)gm * NFEAT + kk);
                    }
                }
                float* a = &As[sr][sc0 + q * 4];
                a[0] = v.x; a[1] = v.y; a[2] = v.z; a[3] = v.w;
            }
        }
        // ---- stage W tile [128 out][32 k]  (concat Wl|Wr along k)
        {
#pragma unroll
            for (int q = 0; q < 4; ++q) {
                const int kk = kb + sc0 + q * 4;
                const float* wp;
                if (AGG) wp = (kk < 128) ? (Wl + sr * NFEAT + kk)
                                         : (Wr + sr * NFEAT + (kk - 128));
                else     wp = Wr + sr * NFEAT + kk;
                const float4 v = *reinterpret_cast<const float4*>(wp);
                float* w = &Ws[sr][sc0 + q * 4];
                w[0] = v.x; w[1] = v.y; w[2] = v.z; w[3] = v.w;
            }
        }
        __syncthreads();
        for (int k = 0; k < BK; ++k) {
            float a[8], b[8];
#pragma unroll
            for (int i = 0; i < 8; ++i) a[i] = As[ty * 8 + i][k];
#pragma unroll
            for (int j = 0; j < 8; ++j) b[j] = Ws[tx * 8 + j][k];
#pragma unroll
            for (int i = 0; i < 8; ++i)
#pragma unroll
                for (int j = 0; j < 8; ++j) acc[i][j] += a[i] * b[j];
        }
        __syncthreads();
    }
    float bv[8];
#pragma unroll
    for (int j = 0; j < 8; ++j) bv[j] = bias[tx * 8 + j];
#pragma unroll
    for (int i = 0; i < 8; ++i) {
        const int gm = m0 + ty * 8 + i;
        if (gm < n) {
            float o[8];
#pragma unroll
            for (int j = 0; j < 8; ++j) {
                float v = acc[i][j] + bv[j];
                if (RELU) v = fmaxf(v, 0.f);
                o[j] = v;
            }
            *reinterpret_cast<float4*>(out + (size_t)gm * NFEAT + tx * 8)     = make_float4(o[0], o[1], o[2], o[3]);
            *reinterpret_cast<float4*>(out + (size_t)gm * NFEAT + tx * 8 + 4) = make_float4(o[4], o[5], o[6], o[7]);
        }
    }
}

extern "C" void kernel_launch(void* const* d_in, const int* in_sizes, int n_in,
                              void* d_out, int out_size, void* d_ws, size_t ws_size,
                              hipStream_t stream) {
    const float* x     = (const float*)d_in[0];
    const int*   xedge = (const int*)d_in[1];
    const float* w1_l  = (const float*)d_in[2];
    const float* b1_l  = (const float*)d_in[3];
    const float* w1_r  = (const float*)d_in[4];
    const float* w2_l  = (const float*)d_in[5];
    const float* b2_l  = (const float*)d_in[6];
    const float* w2_r  = (const float*)d_in[7];
    const float* w_dec = (const float*)d_in[8];
    const float* b_dec = (const float*)d_in[9];

    const int N = in_sizes[0] / NFEAT;
    const int E = in_sizes[1] / 2;
    const int* src = xedge;
    const int* dst = xedge + E;

    float* h_out = (float*)d_out;               // output 0: h  [N,128]
    float* dx    = h_out + (size_t)N * NFEAT;   // output 1: dx [N,128] — also used as mean scratch

    // workspace layout: h1 [N*128 f32] | deg [N] | row_off [N+1] | pos [N] | perm [E]
    char* ws = (char*)d_ws;
    float* h1     = (float*)ws;
    int* deg      = (int*)(ws + (size_t)N * NFEAT * sizeof(float));
    int* row_off  = deg + N;
    int* pos      = row_off + (N + 1);
    int* perm     = pos + N;

    // ---- build CSR (by dst) once; reused by both layers ----
    hipMemsetAsync(deg, 0, (size_t)N * sizeof(int), stream);
    hist_kernel<<<(E + 255) / 256, 256, 0, stream>>>(dst, deg, E);

    const int nb = (N + 1023) / 1024;           // 98 for N=100k (must be <= 256)
    scan_blocks<<<nb, 256, 0, stream>>>(deg, row_off, pos /*bsum scratch*/, N);
    scan_carry<<<1, 256, 0, stream>>>(pos, nb);
    scan_add<<<(N + 255) / 256, 256, 0, stream>>>(row_off, pos, N, E);

    hipMemcpyAsync(pos, row_off, (size_t)N * sizeof(int), hipMemcpyDeviceToDevice, stream);
    fill_csr<<<(E + 255) / 256, 256, 0, stream>>>(src, dst, pos, perm, E);

    const int gab = (N * 4 + 255) / 256 * 4 ? ((N + 3) / 4) : 0;  // 4 nodes (waves) per block
    const int gemmb = (N + 127) / 128;

    // ---- layer 1 ----
    gather_mean<<<(N + 3) / 4, 256, 0, stream>>>(row_off, perm, x, dx /*mean scratch*/, N);
    sage_gemm<true, true><<<gemmb, 256, 0, stream>>>(dx, x, w1_l, w1_r, b1_l, h1, N);

    // ---- layer 2 ----
    gather_mean<<<(N + 3) / 4, 256, 0, stream>>>(row_off, perm, h1, dx /*mean scratch*/, N);
    sage_gemm<true, false><<<gemmb, 256, 0, stream>>>(dx, h1, w2_l, w2_r, b2_l, h_out, N);

    // ---- decoder (overwrites mean scratch with real dx output) ----
    sage_gemm<false, false><<<gemmb, 256, 0, stream>>>(nullptr, h_out, nullptr, w_dec, b_dec, dx, N);
    (void)gab; (void)ws_size; (void)n_in; (void)out_size;
}

// Round 3
// 317.622 us; speedup vs baseline: 7.8915x; 1.9446x over previous
//
#include <hip/hip_runtime.h>

typedef __attribute__((ext_vector_type(8))) short bf16x8;
typedef __attribute__((ext_vector_type(4))) float f32x4;
typedef unsigned int uint;
typedef unsigned short ushort;

#define NFEAT 128

__device__ __forceinline__ ushort f2b(float f) {
    uint u = __float_as_uint(f);
    u = (u + 0x7fffu + ((u >> 16) & 1u)) >> 16;   // RNE
    return (ushort)u;
}

// ---------------- fp32 -> bf16 convert (n multiple of 4) ----------------
__global__ __launch_bounds__(256) void cvt_bf(const float* __restrict__ in,
                                              ushort* __restrict__ out, long n) {
    long i = ((long)blockIdx.x * 256 + threadIdx.x) * 4;
    if (i >= n) return;
    float4 v = *(const float4*)(in + i);
    ushort4 o;
    o.x = f2b(v.x); o.y = f2b(v.y); o.z = f2b(v.z); o.w = f2b(v.w);
    *(ushort4*)(out + i) = o;
}

// ---------------- weight concat [128][256] bf16: [Wl | Wr] along k ----------------
__global__ __launch_bounds__(256) void wcat_k(const float* __restrict__ wl,
                                              const float* __restrict__ wr,
                                              ushort* __restrict__ dst) {
    int i = blockIdx.x * 256 + threadIdx.x;    // 128 blocks x 256 = 32768
    int row = i >> 8, col = i & 255;
    float v = (col < 128) ? wl[row * 128 + col] : wr[row * 128 + col - 128];
    dst[i] = f2b(v);
}

// ---------------- degree histogram (int) ----------------
__global__ void hist_kernel(const int* __restrict__ dst, int* __restrict__ deg, int E) {
    int e = blockIdx.x * blockDim.x + threadIdx.x;
    if (e < E) atomicAdd(&deg[dst[e]], 1);
}

// ---------------- exclusive scan, 3-kernel ----------------
__global__ __launch_bounds__(256) void scan_blocks(const int* __restrict__ in, int* __restrict__ out,
                                                   int* __restrict__ bsum, int n) {
    __shared__ int lds[256];
    const int t = threadIdx.x;
    const int base = blockIdx.x * 1024 + t * 4;
    int a[4];
#pragma unroll
    for (int q = 0; q < 4; ++q) a[q] = (base + q < n) ? in[base + q] : 0;
    const int tsum = a[0] + a[1] + a[2] + a[3];
    lds[t] = tsum;
    __syncthreads();
    for (int off = 1; off < 256; off <<= 1) {
        int v = (t >= off) ? lds[t - off] : 0;
        __syncthreads();
        lds[t] += v;
        __syncthreads();
    }
    const int excl = lds[t] - tsum;
    if (t == 255) bsum[blockIdx.x] = lds[255];
    int r = excl;
#pragma unroll
    for (int q = 0; q < 4; ++q) {
        if (base + q < n) out[base + q] = r;
        r += a[q];
    }
}

__global__ __launch_bounds__(256) void scan_carry(int* __restrict__ bsum, int nb) {
    __shared__ int lds[256];
    const int t = threadIdx.x;
    const int v = (t < nb) ? bsum[t] : 0;
    lds[t] = v;
    __syncthreads();
    for (int off = 1; off < 256; off <<= 1) {
        int u = (t >= off) ? lds[t - off] : 0;
        __syncthreads();
        lds[t] += u;
        __syncthreads();
    }
    if (t < nb) bsum[t] = lds[t] - v;
}

__global__ void scan_add(int* __restrict__ out, const int* __restrict__ bsum, int n, int E) {
    const int i = blockIdx.x * blockDim.x + threadIdx.x;
    if (i < n) out[i] += bsum[i >> 10];
    if (i == 0) out[n] = E;
}

// ---------------- CSR bucket fill ----------------
__global__ void fill_csr(const int* __restrict__ src, const int* __restrict__ dst,
                         int* __restrict__ pos, int* __restrict__ perm, int E) {
    const int e = blockIdx.x * blockDim.x + threadIdx.x;
    if (e < E) {
        const int p = atomicAdd(&pos[dst[e]], 1);
        perm[p] = src[e];
    }
}

// ---------------- gather mean (bf16 in/out, fp32 accumulate): one wave per node --------
__global__ __launch_bounds__(256) void gather_mean_bf(const int* __restrict__ row_off,
                                                      const int* __restrict__ perm,
                                                      const ushort* __restrict__ feat,
                                                      ushort* __restrict__ out, int n) {
    const int node = (blockIdx.x * 256 + threadIdx.x) >> 6;
    if (node >= n) return;
    const int lane = threadIdx.x & 63;
    const int lo = row_off[node], hi = row_off[node + 1];
    float ax = 0.f, ay = 0.f;
    for (int i = lo; i < hi; ++i) {
        const int s = perm[i];
        const uint v = *(const uint*)(feat + (size_t)s * NFEAT + lane * 2);
        ax += __uint_as_float(v << 16);          // col 2*lane   (low ushort)
        ay += __uint_as_float(v & 0xffff0000u);  // col 2*lane+1 (high ushort)
    }
    const float inv = 1.0f / fmaxf((float)(hi - lo), 1.0f);
    uint o = ((uint)f2b(ax * inv)) | (((uint)f2b(ay * inv)) << 16);
    *(uint*)(out + (size_t)node * NFEAT + lane * 2) = o;
}

// ---------------- bf16 MFMA GEMM ----------------
// out[row][col] = sum_k A[row][k] * Wcat[col][k] + bias[col]   (A = [mean|xin] when KT=4)
// block: 128 rows x 128 cols, 4 waves (wave = 32 rows), BK=64, K = KT*64
// LDS tiles XOR-swizzled: byte ^= (row&7)<<4 on BOTH write and read (16B chunks)
template <int KT, bool RELU>
__global__ __launch_bounds__(256) void sage_mfma(
    const ushort* __restrict__ Amean, const ushort* __restrict__ Axin,
    const ushort* __restrict__ Wcat, const float* __restrict__ bias,
    float* __restrict__ outf, ushort* __restrict__ outb, int n)
{
    __shared__ uint4 AsBuf[1024];   // 128 rows x 64 bf16, swizzled
    __shared__ uint4 WsBuf[1024];
    char* As = (char*)AsBuf;
    char* Ws = (char*)WsBuf;
    const int t = threadIdx.x;
    const int m0 = blockIdx.x * 128;
    const int lane = t & 63;
    const int wid = t >> 6;
    const int lrow = lane & 15;
    const int lq = lane >> 4;

    f32x4 acc[2][8];
#pragma unroll
    for (int m = 0; m < 2; ++m)
#pragma unroll
        for (int nn = 0; nn < 8; ++nn) acc[m][nn] = (f32x4){0.f, 0.f, 0.f, 0.f};

    for (int kt = 0; kt < KT; ++kt) {
        const ushort* Abase;
        int co;
        if (KT == 4) { Abase = (kt < 2) ? Amean : Axin; co = (kt & 1) * 64; }
        else         { Abase = Axin;                    co = kt * 64; }
        // ---- stage A tile: 1024 x 16B chunks (8 chunks per row)
#pragma unroll
        for (int i = 0; i < 4; ++i) {
            const int c = t + i * 256;
            const int row = c >> 3, cL = c & 7;
            const int gm = m0 + row;
            uint4 v = make_uint4(0, 0, 0, 0);
            if (gm < n) v = *(const uint4*)((const char*)Abase + ((size_t)gm * NFEAT + co) * 2 + cL * 16);
            *(uint4*)(As + row * 128 + ((cL * 16) ^ ((row & 7) << 4))) = v;
        }
        // ---- stage W tile
#pragma unroll
        for (int i = 0; i < 4; ++i) {
            const int c = t + i * 256;
            const int row = c >> 3, cL = c & 7;
            const uint4 v = *(const uint4*)((const char*)Wcat + ((size_t)row * (KT * 64) + kt * 64) * 2 + cL * 16);
            *(uint4*)(Ws + row * 128 + ((cL * 16) ^ ((row & 7) << 4))) = v;
        }
        __syncthreads();
        // ---- 2 k-steps of 32, 16 MFMA each
#pragma unroll
        for (int ks = 0; ks < 2; ++ks) {
            bf16x8 af[2], bfr[8];
#pragma unroll
            for (int m = 0; m < 2; ++m) {
                const int row = wid * 32 + m * 16 + lrow;
                af[m] = *(const bf16x8*)(As + row * 128 + (((ks * 4 + lq) * 16) ^ ((row & 7) << 4)));
            }
#pragma unroll
            for (int nn = 0; nn < 8; ++nn) {
                const int row = nn * 16 + lrow;
                bfr[nn] = *(const bf16x8*)(Ws + row * 128 + (((ks * 4 + lq) * 16) ^ ((row & 7) << 4)));
            }
#pragma unroll
            for (int m = 0; m < 2; ++m)
#pragma unroll
                for (int nn = 0; nn < 8; ++nn)
                    acc[m][nn] = __builtin_amdgcn_mfma_f32_16x16x32_bf16(af[m], bfr[nn], acc[m][nn], 0, 0, 0);
        }
        __syncthreads();
    }
    // ---- epilogue: C/D layout col=lane&15, row=(lane>>4)*4+reg
#pragma unroll
    for (int m = 0; m < 2; ++m) {
#pragma unroll
        for (int nn = 0; nn < 8; ++nn) {
            const int col = nn * 16 + lrow;
            const float bv = bias[col];
#pragma unroll
            for (int r = 0; r < 4; ++r) {
                const int row = m0 + wid * 32 + m * 16 + lq * 4 + r;
                if (row < n) {
                    float v = acc[m][nn][r] + bv;
                    if (RELU) v = fmaxf(v, 0.f);
                    if (outf) outf[(size_t)row * NFEAT + col] = v;
                    if (outb) outb[(size_t)row * NFEAT + col] = f2b(v);
                }
            }
        }
    }
}

extern "C" void kernel_launch(void* const* d_in, const int* in_sizes, int n_in,
                              void* d_out, int out_size, void* d_ws, size_t ws_size,
                              hipStream_t stream) {
    const float* x     = (const float*)d_in[0];
    const int*   xedge = (const int*)d_in[1];
    const float* w1_l  = (const float*)d_in[2];
    const float* b1_l  = (const float*)d_in[3];
    const float* w1_r  = (const float*)d_in[4];
    const float* w2_l  = (const float*)d_in[5];
    const float* b2_l  = (const float*)d_in[6];
    const float* w2_r  = (const float*)d_in[7];
    const float* w_dec = (const float*)d_in[8];
    const float* b_dec = (const float*)d_in[9];

    const int N = in_sizes[0] / NFEAT;
    const int E = in_sizes[1] / 2;
    const int* src = xedge;
    const int* dst = xedge + E;

    float* h_out = (float*)d_out;                 // output 0: h  [N,128] fp32
    float* dxp   = h_out + (size_t)N * NFEAT;     // output 1: dx [N,128] fp32
    ushort* mean_bf = (ushort*)dxp;               // mean scratch lives in dx region

    // ws: x_bf | h1_bf | h_bf | wc1 | wc2 | wdec | deg | row_off | pos | perm
    char* ws = (char*)d_ws;
    ushort* x_bf  = (ushort*)ws;
    ushort* h1_bf = x_bf  + (size_t)N * NFEAT;
    ushort* h_bf  = h1_bf + (size_t)N * NFEAT;
    ushort* wc1   = h_bf  + (size_t)N * NFEAT;
    ushort* wc2   = wc1 + 128 * 256;
    ushort* wdec  = wc2 + 128 * 256;
    int* deg      = (int*)(wdec + 128 * 128);
    int* row_off  = deg + N;
    int* pos      = row_off + (N + 1);
    int* perm     = pos + N;

    // ---- converts ----
    const long nx = (long)N * NFEAT;
    cvt_bf<<<(int)((nx / 4 + 255) / 256), 256, 0, stream>>>(x, x_bf, nx);
    wcat_k<<<128, 256, 0, stream>>>(w1_l, w1_r, wc1);
    wcat_k<<<128, 256, 0, stream>>>(w2_l, w2_r, wc2);
    cvt_bf<<<16, 256, 0, stream>>>(w_dec, wdec, 128 * 128);

    // ---- build CSR (by dst), reused by both layers ----
    hipMemsetAsync(deg, 0, (size_t)N * sizeof(int), stream);
    hist_kernel<<<(E + 255) / 256, 256, 0, stream>>>(dst, deg, E);
    const int nb = (N + 1023) / 1024;            // must be <= 256
    scan_blocks<<<nb, 256, 0, stream>>>(deg, row_off, pos /*bsum*/, N);
    scan_carry<<<1, 256, 0, stream>>>(pos, nb);
    scan_add<<<(N + 255) / 256, 256, 0, stream>>>(row_off, pos, N, E);
    hipMemcpyAsync(pos, row_off, (size_t)N * sizeof(int), hipMemcpyDeviceToDevice, stream);
    fill_csr<<<(E + 255) / 256, 256, 0, stream>>>(src, dst, pos, perm, E);

    const int gb = (N + 127) / 128;

    // ---- layer 1 ----
    gather_mean_bf<<<(N + 3) / 4, 256, 0, stream>>>(row_off, perm, x_bf, mean_bf, N);
    sage_mfma<4, true><<<gb, 256, 0, stream>>>(mean_bf, x_bf, wc1, b1_l, nullptr, h1_bf, N);

    // ---- layer 2 ----
    gather_mean_bf<<<(N + 3) / 4, 256, 0, stream>>>(row_off, perm, h1_bf, mean_bf, N);
    sage_mfma<4, false><<<gb, 256, 0, stream>>>(mean_bf, h1_bf, wc2, b2_l, h_out, h_bf, N);

    // ---- decoder (overwrites mean scratch region with real dx) ----
    sage_mfma<2, false><<<gb, 256, 0, stream>>>(nullptr, h_bf, wdec, b_dec, dxp, nullptr, N);

    (void)n_in; (void)out_size; (void)ws_size;
}

// Round 4
// 241.865 us; speedup vs baseline: 10.3632x; 1.3132x over previous
//
#include <hip/hip_runtime.h>

typedef __attribute__((ext_vector_type(8))) short bf16x8;
typedef __attribute__((ext_vector_type(4))) float f32x4;
typedef unsigned int uint;
typedef unsigned short ushort;

#define NFEAT 128

__device__ __forceinline__ ushort f2b(float f) {
    uint u = __float_as_uint(f);
    u = (u + 0x7fffu + ((u >> 16) & 1u)) >> 16;   // RNE
    return (ushort)u;
}

// ---------------- fp32 -> bf16 convert (n multiple of 4) ----------------
__global__ __launch_bounds__(256) void cvt_bf(const float* __restrict__ in,
                                              ushort* __restrict__ out, long n) {
    long i = ((long)blockIdx.x * 256 + threadIdx.x) * 4;
    if (i >= n) return;
    float4 v = *(const float4*)(in + i);
    ushort4 o;
    o.x = f2b(v.x); o.y = f2b(v.y); o.z = f2b(v.z); o.w = f2b(v.w);
    *(ushort4*)(out + i) = o;
}

// ---------------- weight concat [128][256] bf16: [Wl | Wr] along k ----------------
__global__ __launch_bounds__(256) void wcat_k(const float* __restrict__ wl,
                                              const float* __restrict__ wr,
                                              ushort* __restrict__ dst) {
    int i = blockIdx.x * 256 + threadIdx.x;    // 128 blocks x 256
    int row = i >> 8, col = i & 255;
    float v = (col < 128) ? wl[row * 128 + col] : wr[row * 128 + col - 128];
    dst[i] = f2b(v);
}

// ---------------- degree histogram (int) ----------------
__global__ void hist_kernel(const int* __restrict__ dst, int* __restrict__ deg, int E) {
    int e = blockIdx.x * blockDim.x + threadIdx.x;
    if (e < E) atomicAdd(&deg[dst[e]], 1);
}

// ---------------- exclusive scan, 3-kernel ----------------
__global__ __launch_bounds__(256) void scan_blocks(const int* __restrict__ in, int* __restrict__ out,
                                                   int* __restrict__ bsum, int n) {
    __shared__ int lds[256];
    const int t = threadIdx.x;
    const int base = blockIdx.x * 1024 + t * 4;
    int a[4];
#pragma unroll
    for (int q = 0; q < 4; ++q) a[q] = (base + q < n) ? in[base + q] : 0;
    const int tsum = a[0] + a[1] + a[2] + a[3];
    lds[t] = tsum;
    __syncthreads();
    for (int off = 1; off < 256; off <<= 1) {
        int v = (t >= off) ? lds[t - off] : 0;
        __syncthreads();
        lds[t] += v;
        __syncthreads();
    }
    const int excl = lds[t] - tsum;
    if (t == 255) bsum[blockIdx.x] = lds[255];
    int r = excl;
#pragma unroll
    for (int q = 0; q < 4; ++q) {
        if (base + q < n) out[base + q] = r;
        r += a[q];
    }
}

__global__ __launch_bounds__(256) void scan_carry(int* __restrict__ bsum, int nb) {
    __shared__ int lds[256];
    const int t = threadIdx.x;
    const int v = (t < nb) ? bsum[t] : 0;
    lds[t] = v;
    __syncthreads();
    for (int off = 1; off < 256; off <<= 1) {
        int u = (t >= off) ? lds[t - off] : 0;
        __syncthreads();
        lds[t] += u;
        __syncthreads();
    }
    if (t < nb) bsum[t] = lds[t] - v;
}

__global__ void scan_add(int* __restrict__ out, const int* __restrict__ bsum, int n, int E) {
    const int i = blockIdx.x * blockDim.x + threadIdx.x;
    if (i < n) out[i] += bsum[i >> 10];
    if (i == 0) out[n] = E;
}

// ---------------- CSR bucket fill ----------------
__global__ void fill_csr(const int* __restrict__ src, const int* __restrict__ dst,
                         int* __restrict__ pos, int* __restrict__ perm, int E) {
    const int e = blockIdx.x * blockDim.x + threadIdx.x;
    if (e < E) {
        const int p = atomicAdd(&pos[dst[e]], 1);
        perm[p] = src[e];
    }
}

// ---------------- gather mean: one wave per node, 4 edges in flight ----------------
// lane = sub(2b) | chunk(4b): 16 lanes x 16B cover a 256B bf16 row; 4 subgroups
// walk interleaved edges; 2-deep unroll -> up to 8 row-loads in flight per wave.
__global__ __launch_bounds__(256) void gather_mean_bf(const int* __restrict__ row_off,
                                                      const int* __restrict__ perm,
                                                      const ushort* __restrict__ feat,
                                                      ushort* __restrict__ out, int n) {
    const int node = (blockIdx.x * 256 + threadIdx.x) >> 6;
    if (node >= n) return;
    const int lane = threadIdx.x & 63;
    const int chunk = lane & 15;
    const int sub = lane >> 4;
    const int lo = row_off[node], hi = row_off[node + 1];
    float acc[8] = {0.f, 0.f, 0.f, 0.f, 0.f, 0.f, 0.f, 0.f};
    int i = lo + sub;
    for (; i + 4 < hi; i += 8) {
        const int s0 = perm[i], s1 = perm[i + 4];
        const uint4 v0 = *(const uint4*)(feat + (size_t)s0 * NFEAT + chunk * 8);
        const uint4 v1 = *(const uint4*)(feat + (size_t)s1 * NFEAT + chunk * 8);
        const uint p0[4] = {v0.x, v0.y, v0.z, v0.w};
        const uint p1[4] = {v1.x, v1.y, v1.z, v1.w};
#pragma unroll
        for (int q = 0; q < 4; ++q) {
            acc[2 * q]     += __uint_as_float(p0[q] << 16);
            acc[2 * q + 1] += __uint_as_float(p0[q] & 0xffff0000u);
            acc[2 * q]     += __uint_as_float(p1[q] << 16);
            acc[2 * q + 1] += __uint_as_float(p1[q] & 0xffff0000u);
        }
    }
    if (i < hi) {
        const int s = perm[i];
        const uint4 v = *(const uint4*)(feat + (size_t)s * NFEAT + chunk * 8);
        const uint p[4] = {v.x, v.y, v.z, v.w};
#pragma unroll
        for (int q = 0; q < 4; ++q) {
            acc[2 * q]     += __uint_as_float(p[q] << 16);
            acc[2 * q + 1] += __uint_as_float(p[q] & 0xffff0000u);
        }
    }
    // reduce across the 4 subgroups (lanes differing in bits 4,5)
#pragma unroll
    for (int q = 0; q < 8; ++q) {
        acc[q] += __shfl_xor(acc[q], 16);
        acc[q] += __shfl_xor(acc[q], 32);
    }
    if (sub == 0) {
        const float inv = 1.0f / fmaxf((float)(hi - lo), 1.0f);
        ushort o[8];
#pragma unroll
        for (int q = 0; q < 8; ++q) o[q] = f2b(acc[q] * inv);
        *(uint4*)(out + (size_t)node * NFEAT + chunk * 8) = *(const uint4*)o;
    }
}

// ---------------- bf16 MFMA GEMM (+ optional fused decoder) ----------------
// out[row][col] = sum_k A[row][k] * Wcat[col][k] + bias[col]   (A = [mean|xin], K=256)
// block: 128 rows x 128 cols, 4 waves (wave = 32 rows), BK=64
// LDS XOR-swizzle byte ^= (row&7)<<4 on BOTH write and read.
// DEC: after h epilogue, each wave stages its own 32x128 bf16 h-tile in its LDS
// quarter and computes dx = h @ Wdec^T + bdec with 64 more MFMAs (wdec from L2).
template <bool RELU, bool DEC>
__global__ __launch_bounds__(256) void sage_mfma(
    const ushort* __restrict__ Amean, const ushort* __restrict__ Axin,
    const ushort* __restrict__ Wcat, const float* __restrict__ bias,
    const ushort* __restrict__ Wdec, const float* __restrict__ bdec,
    float* __restrict__ outf, ushort* __restrict__ outb,
    float* __restrict__ dxp, int n)
{
    __shared__ uint4 smem4[2048];            // 32 KiB
    char* As = (char*)smem4;                 // [128 rows][64 bf16] swizzled
    char* Ws = As + 16384;
    const int t = threadIdx.x;
    const int m0 = blockIdx.x * 128;
    const int lane = t & 63;
    const int wid = t >> 6;
    const int lrow = lane & 15;
    const int lq = lane >> 4;

    f32x4 acc[2][8];
#pragma unroll
    for (int m = 0; m < 2; ++m)
#pragma unroll
        for (int nn = 0; nn < 8; ++nn) acc[m][nn] = (f32x4){0.f, 0.f, 0.f, 0.f};

    for (int kt = 0; kt < 4; ++kt) {
        const ushort* Abase = (kt < 2) ? Amean : Axin;
        const int co = (kt & 1) * 64;
#pragma unroll
        for (int i = 0; i < 4; ++i) {
            const int c = t + i * 256;
            const int row = c >> 3, cL = c & 7;
            const int gm = m0 + row;
            uint4 v = make_uint4(0, 0, 0, 0);
            if (gm < n) v = *(const uint4*)((const char*)Abase + ((size_t)gm * NFEAT + co) * 2 + cL * 16);
            *(uint4*)(As + row * 128 + ((cL * 16) ^ ((row & 7) << 4))) = v;
        }
#pragma unroll
        for (int i = 0; i < 4; ++i) {
            const int c = t + i * 256;
            const int row = c >> 3, cL = c & 7;
            const uint4 v = *(const uint4*)((const char*)Wcat + ((size_t)row * 256 + kt * 64) * 2 + cL * 16);
            *(uint4*)(Ws + row * 128 + ((cL * 16) ^ ((row & 7) << 4))) = v;
        }
        __syncthreads();
#pragma unroll
        for (int ks = 0; ks < 2; ++ks) {
            bf16x8 af[2], bfr[8];
#pragma unroll
            for (int m = 0; m < 2; ++m) {
                const int row = wid * 32 + m * 16 + lrow;
                af[m] = *(const bf16x8*)(As + row * 128 + (((ks * 4 + lq) * 16) ^ ((row & 7) << 4)));
            }
#pragma unroll
            for (int nn = 0; nn < 8; ++nn) {
                const int row = nn * 16 + lrow;
                bfr[nn] = *(const bf16x8*)(Ws + row * 128 + (((ks * 4 + lq) * 16) ^ ((row & 7) << 4)));
            }
#pragma unroll
            for (int m = 0; m < 2; ++m)
#pragma unroll
                for (int nn = 0; nn < 8; ++nn)
                    acc[m][nn] = __builtin_amdgcn_mfma_f32_16x16x32_bf16(af[m], bfr[nn], acc[m][nn], 0, 0, 0);
        }
        __syncthreads();
    }
    // ---- h epilogue: C/D layout col=lane&15, row=(lane>>4)*4+reg
    char* Lh = As;   // DEC: full 32KB as [128 rows][128 bf16] swizzled (wave-private quarters)
#pragma unroll
    for (int m = 0; m < 2; ++m) {
#pragma unroll
        for (int nn = 0; nn < 8; ++nn) {
            const int col = nn * 16 + lrow;
            const float bv = bias[col];
#pragma unroll
            for (int r = 0; r < 4; ++r) {
                const int row = wid * 32 + m * 16 + lq * 4 + r;
                const int grow = m0 + row;
                float v = acc[m][nn][r] + bv;
                if (RELU) v = fmaxf(v, 0.f);
                if (grow < n) {
                    if (outf) outf[(size_t)grow * NFEAT + col] = v;
                    if (outb) outb[(size_t)grow * NFEAT + col] = f2b(v);
                }
                if (DEC)
                    *(ushort*)(Lh + row * 256 + ((col * 2) ^ ((row & 7) << 4))) = f2b(v);
            }
        }
    }
    if (DEC) {
        // wave-private: no barrier needed (each wave reads only its own 32 rows)
        f32x4 acc2[2][8];
#pragma unroll
        for (int m = 0; m < 2; ++m)
#pragma unroll
            for (int nn = 0; nn < 8; ++nn) acc2[m][nn] = (f32x4){0.f, 0.f, 0.f, 0.f};
#pragma unroll
        for (int ks = 0; ks < 4; ++ks) {
            bf16x8 af2[2], bf2[8];
#pragma unroll
            for (int m = 0; m < 2; ++m) {
                const int row = wid * 32 + m * 16 + lrow;
                af2[m] = *(const bf16x8*)(Lh + row * 256 + ((ks * 64 + lq * 16) ^ ((row & 7) << 4)));
            }
#pragma unroll
            for (int nn = 0; nn < 8; ++nn)
                bf2[nn] = *(const bf16x8*)((const char*)Wdec + ((nn * 16 + lrow) * NFEAT + ks * 32 + lq * 8) * 2);
#pragma unroll
            for (int m = 0; m < 2; ++m)
#pragma unroll
                for (int nn = 0; nn < 8; ++nn)
                    acc2[m][nn] = __builtin_amdgcn_mfma_f32_16x16x32_bf16(af2[m], bf2[nn], acc2[m][nn], 0, 0, 0);
        }
#pragma unroll
        for (int m = 0; m < 2; ++m) {
#pragma unroll
            for (int nn = 0; nn < 8; ++nn) {
                const int col = nn * 16 + lrow;
                const float bv = bdec[col];
#pragma unroll
                for (int r = 0; r < 4; ++r) {
                    const int grow = m0 + wid * 32 + m * 16 + lq * 4 + r;
                    if (grow < n) dxp[(size_t)grow * NFEAT + col] = acc2[m][nn][r] + bv;
                }
            }
        }
    }
}

extern "C" void kernel_launch(void* const* d_in, const int* in_sizes, int n_in,
                              void* d_out, int out_size, void* d_ws, size_t ws_size,
                              hipStream_t stream) {
    const float* x     = (const float*)d_in[0];
    const int*   xedge = (const int*)d_in[1];
    const float* w1_l  = (const float*)d_in[2];
    const float* b1_l  = (const float*)d_in[3];
    const float* w1_r  = (const float*)d_in[4];
    const float* w2_l  = (const float*)d_in[5];
    const float* b2_l  = (const float*)d_in[6];
    const float* w2_r  = (const float*)d_in[7];
    const float* w_dec = (const float*)d_in[8];
    const float* b_dec = (const float*)d_in[9];

    const int N = in_sizes[0] / NFEAT;
    const int E = in_sizes[1] / 2;
    const int* src = xedge;
    const int* dst = xedge + E;

    float* h_out = (float*)d_out;                 // output 0: h  [N,128] fp32
    float* dxp   = h_out + (size_t)N * NFEAT;     // output 1: dx [N,128] fp32

    // ws: x_bf | h1_bf | mean_bf | wc1 | wc2 | wdec | deg | row_off | pos | perm
    char* ws = (char*)d_ws;
    ushort* x_bf    = (ushort*)ws;
    ushort* h1_bf   = x_bf   + (size_t)N * NFEAT;
    ushort* mean_bf = h1_bf  + (size_t)N * NFEAT;
    ushort* wc1     = mean_bf + (size_t)N * NFEAT;
    ushort* wc2     = wc1 + 128 * 256;
    ushort* wdec    = wc2 + 128 * 256;
    int* deg        = (int*)(wdec + 128 * 128);
    int* row_off    = deg + N;
    int* pos        = row_off + (N + 1);
    int* perm       = pos + N;

    // ---- converts ----
    const long nx = (long)N * NFEAT;
    cvt_bf<<<(int)((nx / 4 + 255) / 256), 256, 0, stream>>>(x, x_bf, nx);
    wcat_k<<<128, 256, 0, stream>>>(w1_l, w1_r, wc1);
    wcat_k<<<128, 256, 0, stream>>>(w2_l, w2_r, wc2);
    cvt_bf<<<16, 256, 0, stream>>>(w_dec, wdec, 128 * 128);

    // ---- build CSR (by dst), reused by both layers ----
    hipMemsetAsync(deg, 0, (size_t)N * sizeof(int), stream);
    hist_kernel<<<(E + 255) / 256, 256, 0, stream>>>(dst, deg, E);
    const int nb = (N + 1023) / 1024;            // must be <= 256
    scan_blocks<<<nb, 256, 0, stream>>>(deg, row_off, pos /*bsum*/, N);
    scan_carry<<<1, 256, 0, stream>>>(pos, nb);
    scan_add<<<(N + 255) / 256, 256, 0, stream>>>(row_off, pos, N, E);
    hipMemcpyAsync(pos, row_off, (size_t)N * sizeof(int), hipMemcpyDeviceToDevice, stream);
    fill_csr<<<(E + 255) / 256, 256, 0, stream>>>(src, dst, pos, perm, E);

    const int gb = (N + 127) / 128;

    // ---- layer 1 ----
    gather_mean_bf<<<(N + 3) / 4, 256, 0, stream>>>(row_off, perm, x_bf, mean_bf, N);
    sage_mfma<true, false><<<gb, 256, 0, stream>>>(mean_bf, x_bf, wc1, b1_l,
                                                   nullptr, nullptr, nullptr, h1_bf, nullptr, N);

    // ---- layer 2 + fused decoder ----
    gather_mean_bf<<<(N + 3) / 4, 256, 0, stream>>>(row_off, perm, h1_bf, mean_bf, N);
    sage_mfma<false, true><<<gb, 256, 0, stream>>>(mean_bf, h1_bf, wc2, b2_l,
                                                   wdec, b_dec, h_out, nullptr, dxp, N);

    (void)n_in; (void)out_size; (void)ws_size;
}

// Round 5
// 226.206 us; speedup vs baseline: 11.0806x; 1.0692x over previous
//
#include <hip/hip_runtime.h>

typedef __attribute__((ext_vector_type(8))) short bf16x8;
typedef __attribute__((ext_vector_type(4))) float f32x4;
typedef unsigned int uint;
typedef unsigned short ushort;

#define NFEAT 128

__device__ __forceinline__ ushort f2b(float f) {
    uint u = __float_as_uint(f);
    u = (u + 0x7fffu + ((u >> 16) & 1u)) >> 16;   // RNE
    return (ushort)u;
}

// ---------------- fp32 -> bf16 convert (n multiple of 4) ----------------
__global__ __launch_bounds__(256) void cvt_bf(const float* __restrict__ in,
                                              ushort* __restrict__ out, long n) {
    long i = ((long)blockIdx.x * 256 + threadIdx.x) * 4;
    if (i >= n) return;
    float4 v = *(const float4*)(in + i);
    ushort4 o;
    o.x = f2b(v.x); o.y = f2b(v.y); o.z = f2b(v.z); o.w = f2b(v.w);
    *(ushort4*)(out + i) = o;
}

// ---------------- merged weight prep ----------------
// blocks 0..127   -> wc1 [128][256] = [w1_l | w1_r] (bf16, k-concat)
// blocks 128..255 -> wc2 [128][256] = [w2_l | w2_r]
// blocks 256..319 -> wdec [128][128] bf16
__global__ __launch_bounds__(256) void wprep(const float* __restrict__ w1l, const float* __restrict__ w1r,
                                             const float* __restrict__ w2l, const float* __restrict__ w2r,
                                             const float* __restrict__ wd,
                                             ushort* __restrict__ wc1, ushort* __restrict__ wc2,
                                             ushort* __restrict__ wdec) {
    const int b = blockIdx.x;
    if (b < 256) {
        const int i = (b & 127) * 256 + threadIdx.x;
        const int row = i >> 8, col = i & 255;
        const float* wl = (b < 128) ? w1l : w2l;
        const float* wr = (b < 128) ? w1r : w2r;
        ushort* dst = (b < 128) ? wc1 : wc2;
        float v = (col < 128) ? wl[row * 128 + col] : wr[row * 128 + col - 128];
        dst[i] = f2b(v);
    } else {
        const int i = (b - 256) * 256 + threadIdx.x;   // 64*256 = 16384
        wdec[i] = f2b(wd[i]);
    }
}

// ---------------- degree histogram (int) ----------------
__global__ void hist_kernel(const int* __restrict__ dst, int* __restrict__ deg, int E) {
    int e = blockIdx.x * blockDim.x + threadIdx.x;
    if (e < E) atomicAdd(&deg[dst[e]], 1);
}

// ---------------- exclusive scan, 3-kernel ----------------
__global__ __launch_bounds__(256) void scan_blocks(const int* __restrict__ in, int* __restrict__ out,
                                                   int* __restrict__ bsum, int n) {
    __shared__ int lds[256];
    const int t = threadIdx.x;
    const int base = blockIdx.x * 1024 + t * 4;
    int a[4];
#pragma unroll
    for (int q = 0; q < 4; ++q) a[q] = (base + q < n) ? in[base + q] : 0;
    const int tsum = a[0] + a[1] + a[2] + a[3];
    lds[t] = tsum;
    __syncthreads();
    for (int off = 1; off < 256; off <<= 1) {
        int v = (t >= off) ? lds[t - off] : 0;
        __syncthreads();
        lds[t] += v;
        __syncthreads();
    }
    const int excl = lds[t] - tsum;
    if (t == 255) bsum[blockIdx.x] = lds[255];
    int r = excl;
#pragma unroll
    for (int q = 0; q < 4; ++q) {
        if (base + q < n) out[base + q] = r;
        r += a[q];
    }
}

__global__ __launch_bounds__(256) void scan_carry(int* __restrict__ bsum, int nb) {
    __shared__ int lds[256];
    const int t = threadIdx.x;
    const int v = (t < nb) ? bsum[t] : 0;
    lds[t] = v;
    __syncthreads();
    for (int off = 1; off < 256; off <<= 1) {
        int u = (t >= off) ? lds[t - off] : 0;
        __syncthreads();
        lds[t] += u;
        __syncthreads();
    }
    if (t < nb) bsum[t] = lds[t] - v;
}

// adds block carries; writes BOTH row_off and pos (separate bsum -> no race)
__global__ void scan_add(int* __restrict__ row_off, int* __restrict__ pos,
                         const int* __restrict__ bsum, int n, int E) {
    const int i = blockIdx.x * blockDim.x + threadIdx.x;
    if (i < n) {
        const int v = row_off[i] + bsum[i >> 10];
        row_off[i] = v;
        pos[i] = v;
    }
    if (i == 0) row_off[n] = E;
}

// ---------------- CSR bucket fill ----------------
__global__ void fill_csr(const int* __restrict__ src, const int* __restrict__ dst,
                         int* __restrict__ pos, int* __restrict__ perm, int E) {
    const int e = blockIdx.x * blockDim.x + threadIdx.x;
    if (e < E) {
        const int p = atomicAdd(&pos[dst[e]], 1);
        perm[p] = src[e];
    }
}

// ---------------- gather mean: one wave per node, 4 edge-subgroups ----------------
__global__ __launch_bounds__(256) void gather_mean_bf(const int* __restrict__ row_off,
                                                      const int* __restrict__ perm,
                                                      const ushort* __restrict__ feat,
                                                      ushort* __restrict__ out, int n) {
    const int node = (blockIdx.x * 256 + threadIdx.x) >> 6;
    if (node >= n) return;
    const int lane = threadIdx.x & 63;
    const int chunk = lane & 15;
    const int sub = lane >> 4;
    const int lo = row_off[node], hi = row_off[node + 1];
    float acc[8] = {0.f, 0.f, 0.f, 0.f, 0.f, 0.f, 0.f, 0.f};
    int i = lo + sub;
    for (; i + 4 < hi; i += 8) {
        const int s0 = perm[i], s1 = perm[i + 4];
        const uint4 v0 = *(const uint4*)(feat + (size_t)s0 * NFEAT + chunk * 8);
        const uint4 v1 = *(const uint4*)(feat + (size_t)s1 * NFEAT + chunk * 8);
        const uint p0[4] = {v0.x, v0.y, v0.z, v0.w};
        const uint p1[4] = {v1.x, v1.y, v1.z, v1.w};
#pragma unroll
        for (int q = 0; q < 4; ++q) {
            acc[2 * q]     += __uint_as_float(p0[q] << 16);
            acc[2 * q + 1] += __uint_as_float(p0[q] & 0xffff0000u);
            acc[2 * q]     += __uint_as_float(p1[q] << 16);
            acc[2 * q + 1] += __uint_as_float(p1[q] & 0xffff0000u);
        }
    }
    if (i < hi) {
        const int s = perm[i];
        const uint4 v = *(const uint4*)(feat + (size_t)s * NFEAT + chunk * 8);
        const uint p[4] = {v.x, v.y, v.z, v.w};
#pragma unroll
        for (int q = 0; q < 4; ++q) {
            acc[2 * q]     += __uint_as_float(p[q] << 16);
            acc[2 * q + 1] += __uint_as_float(p[q] & 0xffff0000u);
        }
    }
#pragma unroll
    for (int q = 0; q < 8; ++q) {
        acc[q] += __shfl_xor(acc[q], 16);
        acc[q] += __shfl_xor(acc[q], 32);
    }
    if (sub == 0) {
        const float inv = 1.0f / fmaxf((float)(hi - lo), 1.0f);
        ushort o[8];
#pragma unroll
        for (int q = 0; q < 8; ++q) o[q] = f2b(acc[q] * inv);
        *(uint4*)(out + (size_t)node * NFEAT + chunk * 8) = *(const uint4*)o;
    }
}

// ---------------- bf16 MFMA GEMM (+ optional fused decoder) ----------------
// out[row][col] = sum_k A[row][k] * Wcat[col][k] + bias[col]   (A = [mean|xin], K=256)
// SWAPPED operands: acc = mfma(W_frag, A_frag) -> C layout row=lane&15 (node row),
// col=(lane>>4)*4+reg  => per-lane 4 consecutive cols -> float4/ushort4 stores.
// LDS XOR-swizzle byte ^= (row&7)<<4 on both write and read.
template <bool RELU, bool DEC>
__global__ __launch_bounds__(256) void sage_mfma(
    const ushort* __restrict__ Amean, const ushort* __restrict__ Axin,
    const ushort* __restrict__ Wcat, const float* __restrict__ bias,
    const ushort* __restrict__ Wdec, const float* __restrict__ bdec,
    float* __restrict__ outf, ushort* __restrict__ outb,
    float* __restrict__ dxp, int n)
{
    __shared__ uint4 smem4[2048];            // 32 KiB
    char* As = (char*)smem4;                 // [128 rows][64 bf16] swizzled
    char* Ws = As + 16384;
    const int t = threadIdx.x;
    const int m0 = blockIdx.x * 128;
    const int lane = t & 63;
    const int wid = t >> 6;
    const int lrow = lane & 15;
    const int lq = lane >> 4;

    f32x4 acc[2][8];
#pragma unroll
    for (int m = 0; m < 2; ++m)
#pragma unroll
        for (int nn = 0; nn < 8; ++nn) acc[m][nn] = (f32x4){0.f, 0.f, 0.f, 0.f};

    for (int kt = 0; kt < 4; ++kt) {
        const ushort* Abase = (kt < 2) ? Amean : Axin;
        const int co = (kt & 1) * 64;
#pragma unroll
        for (int i = 0; i < 4; ++i) {
            const int c = t + i * 256;
            const int row = c >> 3, cL = c & 7;
            const int gm = m0 + row;
            uint4 v = make_uint4(0, 0, 0, 0);
            if (gm < n) v = *(const uint4*)((const char*)Abase + ((size_t)gm * NFEAT + co) * 2 + cL * 16);
            *(uint4*)(As + row * 128 + ((cL * 16) ^ ((row & 7) << 4))) = v;
        }
#pragma unroll
        for (int i = 0; i < 4; ++i) {
            const int c = t + i * 256;
            const int row = c >> 3, cL = c & 7;
            const uint4 v = *(const uint4*)((const char*)Wcat + ((size_t)row * 256 + kt * 64) * 2 + cL * 16);
            *(uint4*)(Ws + row * 128 + ((cL * 16) ^ ((row & 7) << 4))) = v;
        }
        __syncthreads();
#pragma unroll
        for (int ks = 0; ks < 2; ++ks) {
            bf16x8 af[2], bfr[8];
#pragma unroll
            for (int m = 0; m < 2; ++m) {
                const int row = wid * 32 + m * 16 + lrow;
                af[m] = *(const bf16x8*)(As + row * 128 + (((ks * 4 + lq) * 16) ^ ((row & 7) << 4)));
            }
#pragma unroll
            for (int nn = 0; nn < 8; ++nn) {
                const int row = nn * 16 + lrow;
                bfr[nn] = *(const bf16x8*)(Ws + row * 128 + (((ks * 4 + lq) * 16) ^ ((row & 7) << 4)));
            }
#pragma unroll
            for (int m = 0; m < 2; ++m)
#pragma unroll
                for (int nn = 0; nn < 8; ++nn)
                    acc[m][nn] = __builtin_amdgcn_mfma_f32_16x16x32_bf16(bfr[nn], af[m], acc[m][nn], 0, 0, 0);
        }
        __syncthreads();
    }
    // ---- h epilogue (swapped C layout): node row = lane&15, cols = lq*4 + r
    char* Lh = As;   // DEC: [128 rows][128 bf16] swizzled, wave-private quarters
#pragma unroll
    for (int m = 0; m < 2; ++m) {
        const int row = wid * 32 + m * 16 + lrow;
        const int grow = m0 + row;
#pragma unroll
        for (int nn = 0; nn < 8; ++nn) {
            const int colb = nn * 16 + lq * 4;
            const float4 bv = *(const float4*)(bias + colb);
            float v0 = acc[m][nn][0] + bv.x;
            float v1 = acc[m][nn][1] + bv.y;
            float v2 = acc[m][nn][2] + bv.z;
            float v3 = acc[m][nn][3] + bv.w;
            if (RELU) {
                v0 = fmaxf(v0, 0.f); v1 = fmaxf(v1, 0.f);
                v2 = fmaxf(v2, 0.f); v3 = fmaxf(v3, 0.f);
            }
            ushort4 ob;
            ob.x = f2b(v0); ob.y = f2b(v1); ob.z = f2b(v2); ob.w = f2b(v3);
            if (grow < n) {
                if (outf) *(float4*)(outf + (size_t)grow * NFEAT + colb) = make_float4(v0, v1, v2, v3);
                if (outb) *(ushort4*)(outb + (size_t)grow * NFEAT + colb) = ob;
            }
            if (DEC)
                *(ushort4*)(Lh + row * 256 + ((colb * 2) ^ ((row & 7) << 4))) = ob;
        }
    }
    if (DEC) {
        // wave-private quarters: no barrier needed
        f32x4 acc2[2][8];
#pragma unroll
        for (int m = 0; m < 2; ++m)
#pragma unroll
            for (int nn = 0; nn < 8; ++nn) acc2[m][nn] = (f32x4){0.f, 0.f, 0.f, 0.f};
#pragma unroll
        for (int ks = 0; ks < 4; ++ks) {
            bf16x8 af2[2], bf2[8];
#pragma unroll
            for (int m = 0; m < 2; ++m) {
                const int row = wid * 32 + m * 16 + lrow;
                af2[m] = *(const bf16x8*)(Lh + row * 256 + ((ks * 64 + lq * 16) ^ ((row & 7) << 4)));
            }
#pragma unroll
            for (int nn = 0; nn < 8; ++nn)
                bf2[nn] = *(const bf16x8*)(Wdec + (size_t)(nn * 16 + lrow) * NFEAT + ks * 32 + lq * 8);
#pragma unroll
            for (int m = 0; m < 2; ++m)
#pragma unroll
                for (int nn = 0; nn < 8; ++nn)
                    acc2[m][nn] = __builtin_amdgcn_mfma_f32_16x16x32_bf16(bf2[nn], af2[m], acc2[m][nn], 0, 0, 0);
        }
#pragma unroll
        for (int m = 0; m < 2; ++m) {
            const int grow = m0 + wid * 32 + m * 16 + lrow;
            if (grow < n) {
#pragma unroll
                for (int nn = 0; nn < 8; ++nn) {
                    const int colb = nn * 16 + lq * 4;
                    const float4 bv = *(const float4*)(bdec + colb);
                    *(float4*)(dxp + (size_t)grow * NFEAT + colb) =
                        make_float4(acc2[m][nn][0] + bv.x, acc2[m][nn][1] + bv.y,
                                    acc2[m][nn][2] + bv.z, acc2[m][nn][3] + bv.w);
                }
            }
        }
    }
}

extern "C" void kernel_launch(void* const* d_in, const int* in_sizes, int n_in,
                              void* d_out, int out_size, void* d_ws, size_t ws_size,
                              hipStream_t stream) {
    const float* x     = (const float*)d_in[0];
    const int*   xedge = (const int*)d_in[1];
    const float* w1_l  = (const float*)d_in[2];
    const float* b1_l  = (const float*)d_in[3];
    const float* w1_r  = (const float*)d_in[4];
    const float* w2_l  = (const float*)d_in[5];
    const float* b2_l  = (const float*)d_in[6];
    const float* w2_r  = (const float*)d_in[7];
    const float* w_dec = (const float*)d_in[8];
    const float* b_dec = (const float*)d_in[9];

    const int N = in_sizes[0] / NFEAT;
    const int E = in_sizes[1] / 2;
    const int* src = xedge;
    const int* dst = xedge + E;

    float* h_out = (float*)d_out;                 // output 0: h  [N,128] fp32
    float* dxp   = h_out + (size_t)N * NFEAT;     // output 1: dx [N,128] fp32

    // ws: x_bf | h1_bf | mean_bf | wc1 | wc2 | wdec | deg | row_off | pos | bsum | perm
    char* ws = (char*)d_ws;
    ushort* x_bf    = (ushort*)ws;
    ushort* h1_bf   = x_bf   + (size_t)N * NFEAT;
    ushort* mean_bf = h1_bf  + (size_t)N * NFEAT;
    ushort* wc1     = mean_bf + (size_t)N * NFEAT;
    ushort* wc2     = wc1 + 128 * 256;
    ushort* wdec    = wc2 + 128 * 256;
    int* deg        = (int*)(wdec + 128 * 128);
    int* row_off    = deg + N;
    int* pos        = row_off + (N + 1);
    int* bsum       = pos + N;
    int* perm       = bsum + 256;

    // ---- converts ----
    const long nx = (long)N * NFEAT;
    cvt_bf<<<(int)((nx / 4 + 255) / 256), 256, 0, stream>>>(x, x_bf, nx);
    wprep<<<320, 256, 0, stream>>>(w1_l, w1_r, w2_l, w2_r, w_dec, wc1, wc2, wdec);

    // ---- build CSR (by dst), reused by both layers ----
    hipMemsetAsync(deg, 0, (size_t)N * sizeof(int), stream);
    hist_kernel<<<(E + 255) / 256, 256, 0, stream>>>(dst, deg, E);
    const int nb = (N + 1023) / 1024;            // must be <= 256
    scan_blocks<<<nb, 256, 0, stream>>>(deg, row_off, bsum, N);
    scan_carry<<<1, 256, 0, stream>>>(bsum, nb);
    scan_add<<<(N + 255) / 256, 256, 0, stream>>>(row_off, pos, bsum, N, E);
    fill_csr<<<(E + 255) / 256, 256, 0, stream>>>(src, dst, pos, perm, E);

    const int gb = (N + 127) / 128;

    // ---- layer 1 ----
    gather_mean_bf<<<(N + 3) / 4, 256, 0, stream>>>(row_off, perm, x_bf, mean_bf, N);
    sage_mfma<true, false><<<gb, 256, 0, stream>>>(mean_bf, x_bf, wc1, b1_l,
                                                   nullptr, nullptr, nullptr, h1_bf, nullptr, N);

    // ---- layer 2 + fused decoder ----
    gather_mean_bf<<<(N + 3) / 4, 256, 0, stream>>>(row_off, perm, h1_bf, mean_bf, N);
    sage_mfma<false, true><<<gb, 256, 0, stream>>>(mean_bf, h1_bf, wc2, b2_l,
                                                   wdec, b_dec, h_out, nullptr, dxp, N);

    (void)n_in; (void)out_size; (void)ws_size;
}